// Round 11
// baseline (1265.281 us; speedup 1.0000x reference)
//
#include <hip/hip_runtime.h>

typedef __attribute__((ext_vector_type(8))) __bf16 bf16x8;
typedef __attribute__((ext_vector_type(4))) float f32x4;

#define MFMA16(a, b, c) __builtin_amdgcn_mfma_f32_16x16x32_bf16(a, b, c, 0, 0, 0)

#define T_SEQ 512
#define F_IN 32
#define H1 128
#define E2 64
#define ROWS 2          // batch rows per block

__device__ __forceinline__ float bf2f(ushort u) {
    union { uint i; float f; } v; v.i = ((uint)u) << 16; return v.f;
}
__device__ __forceinline__ ushort f2bf(float f) {
    union { float f; uint i; } v; v.f = f;
    uint r = v.i + 0x7fffu + ((v.i >> 16) & 1u);
    return (ushort)(r >> 16);
}
__device__ __forceinline__ float fast_sigmoid(float x) {
    float e = __expf(-x);
    return __builtin_amdgcn_rcpf(1.0f + e);
}
__device__ __forceinline__ float fast_tanh(float x) {
    float e = __expf(-2.0f * x);
    return 2.0f * __builtin_amdgcn_rcpf(1.0f + e) - 1.0f;
}
__device__ __forceinline__ bf16x8 load_w8(const float* p) {
    bf16x8 r;
#pragma unroll
    for (int j = 0; j < 8; ++j) r[j] = (__bf16)p[j];
    return r;
}

// Fused 2-layer LSTM. 256 blocks x 1024 threads (16 waves, 4 waves/SIMD),
// 2 batch rows per block. Weight file split across 16 thin waves so each
// wave needs <=~110 VGPRs -> fits the 128-VGPR/wave cap WITHOUT spilling
// (rounds 7-10 spilled 160 VGPRs of weights to scratch; WRITE_SIZE 8.5MB).
//  Waves 0-7:  L1 GEMM, wave w owns gate-cols [(w*4+j)*16+l15], j=0..3.
//  Waves 8-15: L2 GEMM, wave v=w-8 owns gate-cols [(v*2+j)*16+l15], j=0..1.
// Epilogue: tid<256 one L1 c/h update; tid 256-383 one L2 update;
// tid 384-447 x staging. 2 barriers/step. Split-precision bf16 hi+lo state.
__global__ __launch_bounds__(1024, 1) void lstm_fused(
    const float* __restrict__ x,      // [512][512][32]
    const float* __restrict__ Wih1,   // [512][32]
    const float* __restrict__ Whh1,   // [512][128]
    const float* __restrict__ bih1,   // [512]
    const float* __restrict__ bhh1,   // [512]
    const float* __restrict__ Wih2,   // [256][128]
    const float* __restrict__ Whh2,   // [256][64]
    const float* __restrict__ bih2,   // [256]
    const float* __restrict__ bhh2,   // [256]
    float* __restrict__ out)          // [512][64] fp32
{
    __shared__ ushort xs [16][72];    // x(t): cols 0..31 hi, 32..63 lo
    __shared__ ushort h1s[16][264];   // h1: cols 0..127 hi, 128..255 lo
    __shared__ ushort h2s[16][136];   // h2: cols 0..63 hi, 64..127 lo
    __shared__ float  g1r[ROWS][516]; // raw L1 gates (valid rows only)
    __shared__ float  g2r[ROWS][260]; // raw L2 gates

    const int tid  = threadIdx.x;
    const int wave = tid >> 6;
    const int lane = tid & 63;
    const int l15  = lane & 15;
    const int quad = lane >> 4;
    const int r0   = blockIdx.x * ROWS;
    const bool isL1 = (wave < 8);

    // wf: L1 -> wf[j*4+kt]=Whh1 (j<4), wf[16+j]=Wih1 (20 frags, 80 VGPR)
    //     L2 -> wf[j*4+kt]=Wih2 (j<2), wf[8+j*2+kt]=Whh2 (12 frags)
    bf16x8 wf[20];
    float  bias[4];

    if (isL1) {
#pragma unroll
        for (int j = 0; j < 4; ++j) {
            const int n = (wave * 4 + j) * 16 + l15;
#pragma unroll
            for (int kt = 0; kt < 4; ++kt)
                wf[j * 4 + kt] = load_w8(Whh1 + n * H1 + kt * 32 + quad * 8);
            wf[16 + j] = load_w8(Wih1 + n * F_IN + quad * 8);
            bias[j] = bih1[n] + bhh1[n];
        }
    } else {
        const int v = wave - 8;
#pragma unroll
        for (int j = 0; j < 2; ++j) {
            const int n = (v * 2 + j) * 16 + l15;
#pragma unroll
            for (int kt = 0; kt < 4; ++kt)
                wf[j * 4 + kt] = load_w8(Wih2 + n * H1 + kt * 32 + quad * 8);
#pragma unroll
            for (int kt = 0; kt < 2; ++kt)
                wf[8 + j * 2 + kt] = load_w8(Whh2 + n * E2 + kt * 32 + quad * 8);
            bias[j] = bih2[n] + bhh2[n];
        }
    }

    // zero h states (rows >= ROWS stay zero forever)
    for (int i = tid; i < 16 * 264; i += 1024) ((ushort*)h1s)[i] = 0;
    for (int i = tid; i < 16 * 136; i += 1024) ((ushort*)h2s)[i] = 0;
    __syncthreads();

    // epilogue / staging ownership
    const int e1row = tid >> 7, e1u = tid & 127;            // tid < 256
    const int e2row = (tid - 256) >> 6, e2u = tid & 63;     // 256 <= tid < 384
    const int xrow  = (tid - 384) >> 5, xcol = tid & 31;    // 384 <= tid < 448
    float c1 = 0.0f, c2 = 0.0f;

    const float* xptr = x + ((size_t)(r0 + (xrow & (ROWS - 1))) * T_SEQ) * F_IN + xcol;
    float xreg = (tid >= 384 && tid < 448) ? xptr[0] : 0.0f;

    f32x4 acc[4];

#pragma unroll 1
    for (int tt = 0; tt <= T_SEQ; ++tt) {
        // ---- stage x(tt), prefetch x(tt+1) ----
        if (tt < T_SEQ && tid >= 384 && tid < 448) {
            const ushort h = f2bf(xreg);
            xs[xrow][xcol]      = h;
            xs[xrow][32 + xcol] = f2bf(xreg - bf2f(h));
            if (tt + 1 < T_SEQ) xreg = xptr[(tt + 1) * F_IN];
        }
        __syncthreads();   // B1: xs(tt), h1(tt-1), h2(tt-2) ready

        // ---- GEMM phase ----
        if (isL1) {
            if (tt < T_SEQ) {
#pragma unroll
                for (int j = 0; j < 4; ++j)
                    acc[j] = (f32x4){bias[j], bias[j], bias[j], bias[j]};
#pragma unroll
                for (int xt = 0; xt < 2; ++xt) {   // x hi, lo
                    const bf16x8 ax = *(const bf16x8*)&xs[l15][xt * 32 + quad * 8];
#pragma unroll
                    for (int j = 0; j < 4; ++j)
                        acc[j] = MFMA16(ax, wf[16 + j], acc[j]);
                }
#pragma unroll
                for (int kt = 0; kt < 8; ++kt) {   // h1 hi (0-3), lo (4-7)
                    const bf16x8 ah = *(const bf16x8*)&h1s[l15][kt * 32 + quad * 8];
#pragma unroll
                    for (int j = 0; j < 4; ++j)
                        acc[j] = MFMA16(ah, wf[j * 4 + (kt & 3)], acc[j]);
                }
                if (quad == 0) {
#pragma unroll
                    for (int j = 0; j < 4; ++j)
#pragma unroll
                        for (int r = 0; r < ROWS; ++r)
                            g1r[r][(wave * 4 + j) * 16 + l15] = acc[j][r];
                }
            }
        } else {
            if (tt >= 1) {
                const int v = wave - 8;
#pragma unroll
                for (int j = 0; j < 2; ++j)
                    acc[j] = (f32x4){bias[j], bias[j], bias[j], bias[j]};
#pragma unroll
                for (int kt = 0; kt < 8; ++kt) {   // h1 hi+lo
                    const bf16x8 a = *(const bf16x8*)&h1s[l15][kt * 32 + quad * 8];
#pragma unroll
                    for (int j = 0; j < 2; ++j)
                        acc[j] = MFMA16(a, wf[j * 4 + (kt & 3)], acc[j]);
                }
#pragma unroll
                for (int kt = 0; kt < 4; ++kt) {   // h2 hi (0-1), lo (2-3)
                    const bf16x8 a = *(const bf16x8*)&h2s[l15][kt * 32 + quad * 8];
#pragma unroll
                    for (int j = 0; j < 2; ++j)
                        acc[j] = MFMA16(a, wf[8 + j * 2 + (kt & 1)], acc[j]);
                }
                if (quad == 0) {
#pragma unroll
                    for (int j = 0; j < 2; ++j)
#pragma unroll
                        for (int r = 0; r < ROWS; ++r)
                            g2r[r][(v * 2 + j) * 16 + l15] = acc[j][r];
                }
            }
        }
        __syncthreads();   // B2: raw gates ready; h/x MFMA reads done

        // ---- epilogue phase ----
        if (tid < 256 && tt < T_SEQ) {
            const float iv = fast_sigmoid(g1r[e1row][e1u]);
            const float fv = fast_sigmoid(g1r[e1row][128 + e1u]);
            const float gv = fast_tanh   (g1r[e1row][256 + e1u]);
            const float ov = fast_sigmoid(g1r[e1row][384 + e1u]);
            const float cn = fv * c1 + iv * gv;
            c1 = cn;
            const float h = ov * fast_tanh(cn);
            const ushort hi = f2bf(h);
            h1s[e1row][e1u]       = hi;
            h1s[e1row][128 + e1u] = f2bf(h - bf2f(hi));
        }
        if (tid >= 256 && tid < 384 && tt >= 1) {
            const float iv = fast_sigmoid(g2r[e2row][e2u]);
            const float fv = fast_sigmoid(g2r[e2row][64 + e2u]);
            const float gv = fast_tanh   (g2r[e2row][128 + e2u]);
            const float ov = fast_sigmoid(g2r[e2row][192 + e2u]);
            const float cn = fv * c2 + iv * gv;
            c2 = cn;
            const float h = ov * fast_tanh(cn);
            const ushort hi = f2bf(h);
            h2s[e2row][e2u]      = hi;
            h2s[e2row][64 + e2u] = f2bf(h - bf2f(hi));
            if (tt == T_SEQ)
                out[(size_t)(r0 + e2row) * E2 + e2u] = h;
        }
    }
}

extern "C" void kernel_launch(void* const* d_in, const int* in_sizes, int n_in,
                              void* d_out, int out_size, void* d_ws, size_t ws_size,
                              hipStream_t stream) {
    lstm_fused<<<256, 1024, 0, stream>>>(
        (const float*)d_in[0], (const float*)d_in[1], (const float*)d_in[2],
        (const float*)d_in[3], (const float*)d_in[4], (const float*)d_in[5],
        (const float*)d_in[6], (const float*)d_in[7], (const float*)d_in[8],
        (float*)d_out);
}

// Round 12
// 954.054 us; speedup vs baseline: 1.3262x; 1.3262x over previous
//
#include <hip/hip_runtime.h>

typedef __attribute__((ext_vector_type(8))) __bf16 bf16x8;
typedef __attribute__((ext_vector_type(4))) float f32x4;

#define MFMA16(a, b, c) __builtin_amdgcn_mfma_f32_16x16x32_bf16(a, b, c, 0, 0, 0)

#define T_SEQ 512
#define F_IN 32
#define H1 128
#define E2 64
#define ROWS 2          // batch rows per block

__device__ __forceinline__ float bf2f(ushort u) {
    union { uint i; float f; } v; v.i = ((uint)u) << 16; return v.f;
}
__device__ __forceinline__ ushort f2bf(float f) {
    union { float f; uint i; } v; v.f = f;
    uint r = v.i + 0x7fffu + ((v.i >> 16) & 1u);
    return (ushort)(r >> 16);
}
__device__ __forceinline__ float fast_sigmoid(float x) {
    float e = __expf(-x);
    return __builtin_amdgcn_rcpf(1.0f + e);
}
__device__ __forceinline__ float fast_tanh(float x) {
    float e = __expf(-2.0f * x);
    return 2.0f * __builtin_amdgcn_rcpf(1.0f + e) - 1.0f;
}
__device__ __forceinline__ bf16x8 load_w8(const float* p) {
    bf16x8 r;
#pragma unroll
    for (int j = 0; j < 8; ++j) r[j] = (__bf16)p[j];
    return r;
}
// LDS-only barrier: orders ds ops across waves WITHOUT draining vmcnt
// (global prefetch loads stay in flight across steps).
__device__ __forceinline__ void bar_lds() {
    __asm__ __volatile__("s_waitcnt lgkmcnt(0)\n\ts_barrier" ::: "memory");
}

// Fused 2-layer LSTM, TWO-PHASE single kernel. 256 blocks x 256 threads
// (4 waves, 1 wave/SIMD -> compiler grants 256 VGPR/wave: cap law
// 65536/threads, measured r6-r11). Each block owns 2 batch rows end-to-end.
// Phase 1: all 4 waves = L1 (wave w -> gate-type w, 8 n-tiles, 40 weight
//   frags = 160 VGPR, register-resident AT LAST). h1(t) bf16-hi -> d_ws
//   (block-private rows; same-CU L2 readback; no cross-block sync).
// Phase 2: same block reloads L2 weights into the same registers (24 frags),
//   streams its own h1 history back with register prefetch.
// Raw lgkm-only barriers keep global prefetch latency off the critical path.
__global__ __launch_bounds__(256, 1) void lstm_fused(
    const float* __restrict__ x,      // [512][512][32]
    const float* __restrict__ Wih1,   // [512][32]
    const float* __restrict__ Whh1,   // [512][128]
    const float* __restrict__ bih1,   // [512]
    const float* __restrict__ bhh1,   // [512]
    const float* __restrict__ Wih2,   // [256][128]
    const float* __restrict__ Whh2,   // [256][64]
    const float* __restrict__ bih2,   // [256]
    const float* __restrict__ bhh2,   // [256]
    ushort* __restrict__ h1ws,        // [512][512][128] bf16 hi (64 MiB d_ws)
    float* __restrict__ out)          // [512][64] fp32
{
    __shared__ ushort xs [16][72];    // x(t): cols 0..31 hi, 32..63 lo
    __shared__ ushort h1s[16][264];   // h1: cols 0..127 hi, 128..255 lo
    __shared__ ushort h2s[16][136];   // h2: cols 0..63 hi, 64..127 lo
    __shared__ float  g1r[ROWS][516]; // raw L1 gates (valid rows only)
    __shared__ float  g2r[ROWS][260]; // raw L2 gates

    const int tid  = threadIdx.x;
    const int wave = tid >> 6;        // = gate type (i,f,g,o) in both phases
    const int lane = tid & 63;
    const int l15  = lane & 15;
    const int quad = lane >> 4;
    const int r0   = blockIdx.x * ROWS;

    bf16x8 wf[40];
    float  bias[8];

    // ---- phase-1 weights: wave w owns L1 gate cols n=(w*8+j)*16+l15 ----
#pragma unroll
    for (int j = 0; j < 8; ++j) {
        const int n = (wave * 8 + j) * 16 + l15;
#pragma unroll
        for (int kt = 0; kt < 4; ++kt)
            wf[j * 4 + kt] = load_w8(Whh1 + n * H1 + kt * 32 + quad * 8);
        wf[32 + j] = load_w8(Wih1 + n * F_IN + quad * 8);
        bias[j] = bih1[n] + bhh1[n];
    }

    // zero LDS state (rows >= ROWS stay zero; garbage rows would only
    // pollute discarded C-rows, but keep clean)
    for (int i = tid; i < 16 * 264; i += 256) ((ushort*)h1s)[i] = 0;
    for (int i = tid; i < 16 * 136; i += 256) ((ushort*)h2s)[i] = 0;
    for (int i = tid; i < 16 * 72;  i += 256) ((ushort*)xs)[i]  = 0;
    __syncthreads();

    // ---------------- PHASE 1: layer 1, t = 0..511 ----------------
    {
        const int e1row = tid >> 7, e1u = tid & 127;   // 1 update/thread
        float c1 = 0.0f;

        const int xrow = tid >> 5, xcol = tid & 31;    // tid < 64 stages x
        const float* xptr = x + ((size_t)(r0 + (xrow & 1)) * T_SEQ) * F_IN + xcol;
        float xreg = (tid < 64) ? xptr[0] : 0.0f;

        f32x4 acc[8];

#pragma unroll 1
        for (int t = 0; t < T_SEQ; ++t) {
            if (tid < 64) {
                const ushort h = f2bf(xreg);
                xs[xrow][xcol]      = h;
                xs[xrow][32 + xcol] = f2bf(xreg - bf2f(h));
                if (t + 1 < T_SEQ) xreg = xptr[(t + 1) * F_IN];
            }
            bar_lds();   // B1: xs(t), h1s(t-1) visible

#pragma unroll
            for (int j = 0; j < 8; ++j)
                acc[j] = (f32x4){bias[j], bias[j], bias[j], bias[j]};
#pragma unroll
            for (int xt = 0; xt < 2; ++xt) {   // x hi, lo
                const bf16x8 ax = *(const bf16x8*)&xs[l15][xt * 32 + quad * 8];
#pragma unroll
                for (int j = 0; j < 8; ++j)
                    acc[j] = MFMA16(ax, wf[32 + j], acc[j]);
            }
#pragma unroll
            for (int kt = 0; kt < 8; ++kt) {   // h1 hi (0-3), lo (4-7)
                const bf16x8 ah = *(const bf16x8*)&h1s[l15][kt * 32 + quad * 8];
#pragma unroll
                for (int j = 0; j < 8; ++j)
                    acc[j] = MFMA16(ah, wf[j * 4 + (kt & 3)], acc[j]);
            }
            if (quad == 0) {
#pragma unroll
                for (int j = 0; j < 8; ++j)
#pragma unroll
                    for (int r = 0; r < ROWS; ++r)
                        g1r[r][(wave * 8 + j) * 16 + l15] = acc[j][r];
            }
            bar_lds();   // B2: g1r ready; h1s/xs reads done

            // epilogue: 2 rows x 128 units = 256 updates, 1 per thread
            {
                const float iv = fast_sigmoid(g1r[e1row][e1u]);
                const float fv = fast_sigmoid(g1r[e1row][128 + e1u]);
                const float gv = fast_tanh   (g1r[e1row][256 + e1u]);
                const float ov = fast_sigmoid(g1r[e1row][384 + e1u]);
                const float cn = fv * c1 + iv * gv;
                c1 = cn;
                const float h = ov * fast_tanh(cn);
                const ushort hi = f2bf(h);
                h1s[e1row][e1u]       = hi;
                h1s[e1row][128 + e1u] = f2bf(h - bf2f(hi));
                h1ws[((size_t)(r0 + e1row) * T_SEQ + t) * H1 + e1u] = hi;
            }
            // next-iter B1 covers h1s visibility
        }
    }

    __syncthreads();   // full drain: phase-1 LDS + global h1 writes complete

    // ---- phase-2 weights: wave w owns L2 gate cols n = w*64 + j*16 + l15 ----
#pragma unroll
    for (int j = 0; j < 4; ++j) {
        const int n = wave * 64 + j * 16 + l15;
#pragma unroll
        for (int kt = 0; kt < 4; ++kt)
            wf[j * 4 + kt] = load_w8(Wih2 + n * H1 + kt * 32 + quad * 8);
#pragma unroll
        for (int kt = 0; kt < 2; ++kt)
            wf[16 + j * 2 + kt] = load_w8(Whh2 + n * E2 + kt * 32 + quad * 8);
        bias[j] = bih2[n] + bhh2[n];
    }

    // ---------------- PHASE 2: layer 2, t = 0..511 ----------------
    {
        const int e2row = tid >> 6, e2u = tid & 63;   // tid < 128: 1 update
        float c2 = 0.0f;

        // h1 readback: tid < 128 owns uint (row = tid>>6, uu = tid&63)
        const uint* uptr = (const uint*)h1ws +
                           ((size_t)(r0 + ((tid >> 6) & 1)) * T_SEQ) * 64 + (tid & 63);
        uint ureg = (tid < 128) ? uptr[0] : 0u;

        f32x4 acc[4];

#pragma unroll 1
        for (int t = 0; t < T_SEQ; ++t) {
            if (tid < 128) {
                *(uint*)&h1s[e2row][2 * e2u] = ureg;   // 2 adjacent bf16 hi
                if (t + 1 < T_SEQ) ureg = uptr[(size_t)(t + 1) * 64];
            }
            bar_lds();   // B1: h1s(t), h2s(t-1) visible

#pragma unroll
            for (int j = 0; j < 4; ++j)
                acc[j] = (f32x4){bias[j], bias[j], bias[j], bias[j]};
#pragma unroll
            for (int kt = 0; kt < 4; ++kt) {   // h1 hi only (cols 0..127)
                const bf16x8 a = *(const bf16x8*)&h1s[l15][kt * 32 + quad * 8];
#pragma unroll
                for (int j = 0; j < 4; ++j)
                    acc[j] = MFMA16(a, wf[j * 4 + kt], acc[j]);
            }
#pragma unroll
            for (int kt = 0; kt < 4; ++kt) {   // h2 hi (0-1), lo (2-3)
                const bf16x8 a = *(const bf16x8*)&h2s[l15][kt * 32 + quad * 8];
#pragma unroll
                for (int j = 0; j < 4; ++j)
                    acc[j] = MFMA16(a, wf[16 + j * 2 + (kt & 1)], acc[j]);
            }
            if (quad == 0) {
#pragma unroll
                for (int j = 0; j < 4; ++j)
#pragma unroll
                    for (int r = 0; r < ROWS; ++r)
                        g2r[r][wave * 64 + j * 16 + l15] = acc[j][r];
            }
            bar_lds();   // B2: g2r ready; h1s/h2s reads done

            if (tid < 128) {
                const float iv = fast_sigmoid(g2r[e2row][e2u]);
                const float fv = fast_sigmoid(g2r[e2row][64 + e2u]);
                const float gv = fast_tanh   (g2r[e2row][128 + e2u]);
                const float ov = fast_sigmoid(g2r[e2row][192 + e2u]);
                const float cn = fv * c2 + iv * gv;
                c2 = cn;
                const float h = ov * fast_tanh(cn);
                const ushort hi = f2bf(h);
                h2s[e2row][e2u]      = hi;
                h2s[e2row][64 + e2u] = f2bf(h - bf2f(hi));
                if (t == T_SEQ - 1)
                    out[(size_t)(r0 + e2row) * E2 + e2u] = h;
            }
        }
    }
}

extern "C" void kernel_launch(void* const* d_in, const int* in_sizes, int n_in,
                              void* d_out, int out_size, void* d_ws, size_t ws_size,
                              hipStream_t stream) {
    lstm_fused<<<256, 256, 0, stream>>>(
        (const float*)d_in[0], (const float*)d_in[1], (const float*)d_in[2],
        (const float*)d_in[3], (const float*)d_in[4], (const float*)d_in[5],
        (const float*)d_in[6], (const float*)d_in[7], (const float*)d_in[8],
        (ushort*)d_ws, (float*)d_out);
}